// Round 10
// baseline (652.268 us; speedup 1.0000x reference)
//
#include <hip/hip_runtime.h>
#include <hip/hip_bf16.h>
#include <hip/hip_cooperative_groups.h>
namespace cg = cooperative_groups;

#define BB 4
#define NN 512
#define CC 32
#define KK 4      // K+1
#define HH 4
#define AOUT 256

// ws float-index offsets (si/sj)
#define WS_SI_F   0
#define WS_SII_F  (BB*NN*HH)
#define WS_SJR_F  (2*BB*NN*HH)
#define WS_SJI_F  (3*BB*NN*HH)
// ws byte offsets
#define XT_BASE   131072         // bf16 X tiles [part][b][jb16] x 2048 B
#define LX_BASE   393216         // bf16 LX [bn] x 2048 B   (4 MB)
#define BRE_BASE  4587520        // bf16 B_re fragments, 128 KB
#define BIM_BASE  4718592        // bf16 B_im fragments, 128 KB

typedef __attribute__((ext_vector_type(8))) short bf16x8;
typedef __attribute__((ext_vector_type(4))) float f32x4;

__device__ __forceinline__ ushort f2bfu(float f){
    union { __hip_bfloat16 h; ushort u; } cv;
    cv.h = __float2bfloat16(f);
    return cv.u;
}
__device__ __forceinline__ short f2bfs(float f){ return (short)f2bfu(f); }
__device__ __forceinline__ float bfu2f(unsigned int u){ return __uint_as_float(u << 16); }

// ---------------------------------------------------------------------------
// Prep bodies (device functions shared by fused + fallback kernels)
// ---------------------------------------------------------------------------
__device__ __forceinline__ void prep_sisj(
    int row, int q,
    const float* __restrict__ Xr, const float* __restrict__ Xi,
    const float* __restrict__ AWr, const float* __restrict__ AWi,
    float* __restrict__ ws)
{
    const float* xr = Xr + (size_t)row*CC + q*8;
    const float* xi = Xi + (size_t)row*CC + q*8;
    float4 xr4[2], xi4[2];
    xr4[0] = *(const float4*)xr;  xr4[1] = *(const float4*)(xr + 4);
    xi4[0] = *(const float4*)xi;  xi4[1] = *(const float4*)(xi + 4);

    float sir[HH] = {0,0,0,0}, sii[HH] = {0,0,0,0};
    float sjr[HH] = {0,0,0,0}, sji[HH] = {0,0,0,0};
    #pragma unroll
    for (int e = 0; e < 8; ++e) {
        float xrc = ((const float*)&xr4[e>>2])[e & 3];
        float xic = ((const float*)&xi4[e>>2])[e & 3];
        int c = q*8 + e;
        float4 w1r = *(const float4*)(AWr + c*HH);
        float4 w1i = *(const float4*)(AWi + c*HH);
        float4 w2r = *(const float4*)(AWr + (CC + c)*HH);
        float4 w2i = *(const float4*)(AWi + (CC + c)*HH);
        #pragma unroll
        for (int h = 0; h < HH; ++h) {
            float r1 = ((const float*)&w1r)[h], i1 = ((const float*)&w1i)[h];
            float r2 = ((const float*)&w2r)[h], i2 = ((const float*)&w2i)[h];
            sir[h] = fmaf(xrc, r1, fmaf(-xic, i1, sir[h]));
            sii[h] = fmaf(xrc, i1, fmaf( xic, r1, sii[h]));
            sjr[h] = fmaf(xrc, r2, fmaf(-xic, i2, sjr[h]));
            sji[h] = fmaf(xrc, i2, fmaf( xic, r2, sji[h]));
        }
    }
    float A[HH], Bv[HH];
    #pragma unroll
    for (int h = 0; h < HH; ++h) {
        float sendA = (q & 1) ? sir[h] : sii[h];
        float keepA = (q & 1) ? sii[h] : sir[h];
        A[h] = keepA + __shfl_xor(sendA, 1);
        float sendB = (q & 1) ? sjr[h] : sji[h];
        float keepB = (q & 1) ? sji[h] : sjr[h];
        Bv[h] = keepB + __shfl_xor(sendB, 1);
    }
    float tot[HH];
    #pragma unroll
    for (int h = 0; h < HH; ++h) {
        float send = (q & 2) ? A[h] : Bv[h];
        float keep = (q & 2) ? Bv[h] : A[h];
        tot[h] = keep + __shfl_xor(send, 2);
    }
    float4 v = make_float4(tot[0], tot[1], tot[2], tot[3]);
    *(float4*)(ws + (size_t)q*(BB*NN*HH) + (size_t)row*HH) = v;
}

__device__ __forceinline__ void prep_packxt(
    int bid2, int lane,
    const float* __restrict__ Xr, const float* __restrict__ Xi,
    char* __restrict__ wsB)
{
    int part = bid2 >> 6, b = (bid2 >> 4) & 3, jb = bid2 & 15;
    const float* X = part ? Xi : Xr;
    int c = lane & 31, jh = lane >> 5;

    unsigned int w[8];
    #pragma unroll
    for (int qq = 0; qq < 8; ++qq) {
        int ji = jh*16 + qq*2;
        float f0 = X[((size_t)b*NN + jb*32 + ji  )*CC + c];
        float f1 = X[((size_t)b*NN + jb*32 + ji+1)*CC + c];
        w[qq] = (unsigned int)f2bfu(f0) | ((unsigned int)f2bfu(f1) << 16);
    }
    char* tile = wsB + XT_BASE + (((size_t)(part*4 + b)*16 + jb) * 2048);
    uint4* dst = (uint4*)(tile + c*64 + jh*32);
    dst[0] = make_uint4(w[0], w[1], w[2], w[3]);
    dst[1] = make_uint4(w[4], w[5], w[6], w[7]);
}

__device__ __forceinline__ void prep_packw(
    int idx,
    const float* __restrict__ Wr, const float* __restrict__ Wi,
    char* __restrict__ wsB)
{
    int l  = idx & 63;
    int s  = (idx >> 6) & 7;
    int Nt = (idx >> 9) & 3;
    int h  = idx >> 11;
    int p = Nt*16 + (l & 15), o = p*4 + h;
    int e8 = (l >> 4) * 8;
    unsigned int re_w[4], im_w[4];
    #pragma unroll
    for (int qq = 0; qq < 4; ++qq) {
        unsigned int rw = 0, iw = 0;
        #pragma unroll
        for (int half = 0; half < 2; ++half) {
            int kpos = s*32 + e8 + qq*2 + half;
            int ri = kpos >> 7, kk = (kpos >> 5) & 3, c = kpos & 31;
            float wr = Wr[(size_t)(kk*CC + c)*AOUT + o];
            float wi = Wi[(size_t)(kk*CC + c)*AOUT + o];
            unsigned int vre = f2bfu(ri ? -wi : wr);
            unsigned int vim = f2bfu(ri ?  wr : wi);
            rw |= vre << (16*half);
            iw |= vim << (16*half);
        }
        re_w[qq] = rw; im_w[qq] = iw;
    }
    size_t fo = ((size_t)((h*4 + Nt)*8 + s))*1024 + (size_t)l*16;
    *(uint4*)(wsB + BRE_BASE + fo) = make_uint4(re_w[0], re_w[1], re_w[2], re_w[3]);
    *(uint4*)(wsB + BIM_BASE + fo) = make_uint4(im_w[0], im_w[1], im_w[2], im_w[3]);
}

// ---------------------------------------------------------------------------
// Main body (the round-5 best: 2-wave, 2-deep p/q pipeline) as device fn
// ---------------------------------------------------------------------------
struct MainLds {
    ushort Lf[8][528];      // 8448 B
    float  awf[HH][520];    // 8320 B (reused as pbuf)
    float  wredm[2][HH];
    float  wreds[2][HH];
};                          // 16832 B total

__device__ __forceinline__ void main_body(
    int bn, int t, MainLds& S,
    const float* __restrict__ Lr_g, const float* __restrict__ Li_g,
    const float* __restrict__ abr, const float* __restrict__ abi,
    const float* __restrict__ par, const float* __restrict__ pai,
    const float* __restrict__ ws, char* __restrict__ wsB)
{
    const int b = bn >> 9;
    const int n = bn & (NN - 1);
    const int l = t & 63;
    const int w = t >> 6;
    const int jw = 4*t;

    // hoisted loads: si, sj
    const float4 si_r4 = *(const float4*)(ws + WS_SI_F  + (size_t)bn*HH);
    const float4 si_i4 = *(const float4*)(ws + WS_SII_F + (size_t)bn*HH);
    float4 sjr[4], sji[4];
    #pragma unroll
    for (int e = 0; e < 4; ++e) {
        sjr[e] = *(const float4*)(ws + WS_SJR_F + ((size_t)b*NN + jw + e)*HH);
        sji[e] = *(const float4*)(ws + WS_SJI_F + ((size_t)b*NN + jw + e)*HH);
    }
    const float a_r = par[0], a_i = pai[0];

    // P1: stage L as bf16; fp32 mask
    float am4[4] = {0.f,0.f,0.f,0.f};
    #pragma unroll
    for (int it = 0; it < 8; ++it) {
        const float* src = (it & 4) ? Li_g : Lr_g;
        size_t goff = (((size_t)b*KK + (it & 3))*NN + n)*NN + jw;
        float4 v = *(const float4*)(src + goff);
        if (it < 4) {
            am4[0] += fabsf(v.x); am4[1] += fabsf(v.y);
            am4[2] += fabsf(v.z); am4[3] += fabsf(v.w);
        }
        ushort4 u;
        u.x = f2bfu(v.x); u.y = f2bfu(v.y); u.z = f2bfu(v.z); u.w = f2bfu(v.w);
        *(ushort4*)&S.Lf[it][jw] = u;
    }

    // P2a: scores in registers
    float sir[HH], sii[HH];
    #pragma unroll
    for (int h = 0; h < HH; ++h) {
        sir[h] = ((const float*)&si_r4)[h] + abr[h];
        sii[h] = ((const float*)&si_i4)[h] + abi[h];
    }
    float v[4][HH];
    float pmax[HH] = {-INFINITY, -INFINITY, -INFINITY, -INFINITY};
    #pragma unroll
    for (int e = 0; e < 4; ++e) {
        bool msk = am4[e] > 1e-9f;
        const float* sjrp = (const float*)&sjr[e];
        const float* sjip = (const float*)&sji[e];
        #pragma unroll
        for (int h = 0; h < HH; ++h) {
            float sr = sir[h] + sjrp[h];
            sr = sr >= 0.f ? sr : a_r * sr;
            float sv = sii[h] + sjip[h];
            sv = sv >= 0.f ? sv : a_i * sv;
            float val;
            if (msk) val = sr*sr + sv*sv;
            else { const float NEG = -1e9f; val = NEG*NEG + NEG*NEG; }
            v[e][h] = val;
            pmax[h] = fmaxf(pmax[h], val);
        }
    }
    #pragma unroll
    for (int h = 0; h < HH; ++h) {
        #pragma unroll
        for (int off = 32; off > 0; off >>= 1)
            pmax[h] = fmaxf(pmax[h], __shfl_xor(pmax[h], off));
    }
    if (l == 0) { S.wredm[w][0]=pmax[0]; S.wredm[w][1]=pmax[1]; S.wredm[w][2]=pmax[2]; S.wredm[w][3]=pmax[3]; }
    __syncthreads();                   // S1

    float hm[HH];
    #pragma unroll
    for (int h = 0; h < HH; ++h) hm[h] = fmaxf(S.wredm[0][h], S.wredm[1][h]);

    // P2b: exp
    float psum[HH];
    #pragma unroll
    for (int h = 0; h < HH; ++h) {
        float4 ev;
        ev.x = __expf(v[0][h] - hm[h]);
        ev.y = __expf(v[1][h] - hm[h]);
        ev.z = __expf(v[2][h] - hm[h]);
        ev.w = __expf(v[3][h] - hm[h]);
        *(float4*)&S.awf[h][jw] = ev;
        psum[h] = (ev.x + ev.y) + (ev.z + ev.w);
    }
    #pragma unroll
    for (int h = 0; h < HH; ++h) {
        #pragma unroll
        for (int off = 32; off > 0; off >>= 1)
            psum[h] += __shfl_xor(psum[h], off);
    }
    if (l == 0) { S.wreds[w][0]=psum[0]; S.wreds[w][1]=psum[1]; S.wreds[w][2]=psum[2]; S.wreds[w][3]=psum[3]; }
    __syncthreads();                   // S2

    float inv[HH];
    #pragma unroll
    for (int h = 0; h < HH; ++h) inv[h] = 1.0f / (S.wreds[0][h] + S.wreds[1][h]);

    // P3: MFMA, wave w owns j in [w*256, w*256+256)
    const int r_a = l & 15;
    const int jg  = l >> 4;
    const int k_a = r_a >> 2, h_a = r_a & 3;

    f32x4 acc[8];
    #pragma unroll
    for (int a = 0; a < 8; ++a) acc[a] = (f32x4){0.f,0.f,0.f,0.f};

    const char* xtR = wsB + XT_BASE + ((size_t)(0*4 + b)*16 + w*8)*2048;
    const char* xtI = wsB + XT_BASE + ((size_t)(4   + b)*16 + w*8)*2048;
    const int bofs = (l & 15)*64 + jg*16;

#define LOAD_STEP(s, BR0,BR1,BI0,BI1, LR8,LI8, AW0,AW1) do {                  \
        const int j0_ = w*256 + (s)*32 + jg*8;                                \
        BR0 = *(const bf16x8*)(xtR + (s)*2048 +        bofs);                 \
        BR1 = *(const bf16x8*)(xtR + (s)*2048 + 1024 + bofs);                 \
        BI0 = *(const bf16x8*)(xtI + (s)*2048 +        bofs);                 \
        BI1 = *(const bf16x8*)(xtI + (s)*2048 + 1024 + bofs);                 \
        LR8 = *(const bf16x8*)&S.Lf[k_a][j0_];                                \
        LI8 = *(const bf16x8*)&S.Lf[4 + k_a][j0_];                            \
        AW0 = *(const float4*)&S.awf[h_a][j0_];                               \
        AW1 = *(const float4*)&S.awf[h_a][j0_ + 4];                           \
    } while (0)

#define COMP_STEP(BR0,BR1,BI0,BI1, LR8,LI8, AW0,AW1) do {                     \
        float aww_[8];                                                        \
        *(float4*)&aww_[0] = AW0; *(float4*)&aww_[4] = AW1;                   \
        bf16x8 Ar_, Ai_;                                                      \
        _Pragma("unroll")                                                     \
        for (int e_ = 0; e_ < 8; ++e_) {                                      \
            Ar_[e_] = f2bfs(bfu2f((ushort)LR8[e_]) * aww_[e_]);               \
            Ai_[e_] = f2bfs(bfu2f((ushort)LI8[e_]) * aww_[e_]);               \
        }                                                                     \
        acc[0] = __builtin_amdgcn_mfma_f32_16x16x32_bf16(Ar_, BR0, acc[0],0,0,0); \
        acc[1] = __builtin_amdgcn_mfma_f32_16x16x32_bf16(Ar_, BR1, acc[1],0,0,0); \
        acc[2] = __builtin_amdgcn_mfma_f32_16x16x32_bf16(Ai_, BI0, acc[2],0,0,0); \
        acc[3] = __builtin_amdgcn_mfma_f32_16x16x32_bf16(Ai_, BI1, acc[3],0,0,0); \
        acc[4] = __builtin_amdgcn_mfma_f32_16x16x32_bf16(Ar_, BI0, acc[4],0,0,0); \
        acc[5] = __builtin_amdgcn_mfma_f32_16x16x32_bf16(Ar_, BI1, acc[5],0,0,0); \
        acc[6] = __builtin_amdgcn_mfma_f32_16x16x32_bf16(Ai_, BR0, acc[6],0,0,0); \
        acc[7] = __builtin_amdgcn_mfma_f32_16x16x32_bf16(Ai_, BR1, acc[7],0,0,0); \
    } while (0)

    {
        bf16x8 pBr0,pBr1,pBi0,pBi1,pLr,pLi; float4 pA0,pA1;
        bf16x8 qBr0,qBr1,qBi0,qBi1,qLr,qLi; float4 qA0,qA1;
        LOAD_STEP(0, pBr0,pBr1,pBi0,pBi1, pLr,pLi, pA0,pA1);
        LOAD_STEP(1, qBr0,qBr1,qBi0,qBi1, qLr,qLi, qA0,qA1);
        COMP_STEP(pBr0,pBr1,pBi0,pBi1, pLr,pLi, pA0,pA1);
        LOAD_STEP(2, pBr0,pBr1,pBi0,pBi1, pLr,pLi, pA0,pA1);
        COMP_STEP(qBr0,qBr1,qBi0,qBi1, qLr,qLi, qA0,qA1);
        LOAD_STEP(3, qBr0,qBr1,qBi0,qBi1, qLr,qLi, qA0,qA1);
        COMP_STEP(pBr0,pBr1,pBi0,pBi1, pLr,pLi, pA0,pA1);
        LOAD_STEP(4, pBr0,pBr1,pBi0,pBi1, pLr,pLi, pA0,pA1);
        COMP_STEP(qBr0,qBr1,qBi0,qBi1, qLr,qLi, qA0,qA1);
        LOAD_STEP(5, qBr0,qBr1,qBi0,qBi1, qLr,qLi, qA0,qA1);
        COMP_STEP(pBr0,pBr1,pBi0,pBi1, pLr,pLi, pA0,pA1);
        LOAD_STEP(6, pBr0,pBr1,pBi0,pBi1, pLr,pLi, pA0,pA1);
        COMP_STEP(qBr0,qBr1,qBi0,qBi1, qLr,qLi, qA0,qA1);
        LOAD_STEP(7, qBr0,qBr1,qBi0,qBi1, qLr,qLi, qA0,qA1);
        COMP_STEP(pBr0,pBr1,pBi0,pBi1, pLr,pLi, pA0,pA1);
        COMP_STEP(qBr0,qBr1,qBi0,qBi1, qLr,qLi, qA0,qA1);
    }
#undef LOAD_STEP
#undef COMP_STEP

    __syncthreads();                   // S3

    float* pbuf = &S.awf[0][0];
    if (w == 1) {
        #pragma unroll
        for (int a = 0; a < 8; ++a)
            #pragma unroll
            for (int r = 0; r < 4; ++r)
                pbuf[(a*4 + r)*64 + l] = acc[a][r];
    }
    __syncthreads();                   // S4
    if (w == 0) {
        const int kk = l >> 4, lc = l & 15;
        #pragma unroll
        for (int a = 0; a < 8; ++a)
            #pragma unroll
            for (int r = 0; r < 4; ++r)
                acc[a][r] += pbuf[(a*4 + r)*64 + l];
        char* lxp = wsB + LX_BASE + (size_t)bn*2048;
        #pragma unroll
        for (int ct = 0; ct < 2; ++ct) {
            const int c = ct*16 + lc;
            #pragma unroll
            for (int r = 0; r < 4; ++r) {   // r == h
                float iv = inv[r];
                float vr = (acc[0+ct][r] - acc[2+ct][r]) * iv;
                float vi = (acc[4+ct][r] + acc[6+ct][r]) * iv;
                *(ushort*)(lxp + r*512 +       kk*64 + c*2) = f2bfu(vr);
                *(ushort*)(lxp + r*512 + 256 + kk*64 + c*2) = f2bfu(vi);
            }
        }
    }
}

// ---------------------------------------------------------------------------
// Out-GEMM body: one wave handles task = Mtile*16 + Nt*4 + h
// ---------------------------------------------------------------------------
__device__ __forceinline__ void out_body(
    int task, int l, const char* __restrict__ wsB,
    const float* __restrict__ bsr, const float* __restrict__ bsi,
    float* __restrict__ out)
{
    const int Mtile = task >> 4;
    const int Nt    = (task >> 2) & 3;
    const int h     = task & 3;

    const char* abase = wsB + LX_BASE + ((size_t)(Mtile*16 + (l & 15)))*2048
                        + h*512 + (l >> 4)*16;
    f32x4 are = (f32x4){0.f,0.f,0.f,0.f};
    f32x4 aim = (f32x4){0.f,0.f,0.f,0.f};
    const size_t fbase = ((size_t)((h*4 + Nt)*8))*1024 + (size_t)l*16;
    const char* bre = wsB + BRE_BASE + fbase;
    const char* bim = wsB + BIM_BASE + fbase;
    #pragma unroll
    for (int s = 0; s < 8; ++s) {
        bf16x8 Af = *(const bf16x8*)(abase + s*64);
        bf16x8 Br = *(const bf16x8*)(bre + s*1024);
        bf16x8 Bi = *(const bf16x8*)(bim + s*1024);
        are = __builtin_amdgcn_mfma_f32_16x16x32_bf16(Af, Br, are, 0, 0, 0);
        aim = __builtin_amdgcn_mfma_f32_16x16x32_bf16(Af, Bi, aim, 0, 0, 0);
    }
    const int p = Nt*16 + (l & 15), o = p*4 + h;
    const float vbr = bsr[o], vbi = bsi[o];
    #pragma unroll
    for (int r = 0; r < 4; ++r) {
        int bn = Mtile*16 + (l >> 4)*4 + r;
        out[(size_t)bn*AOUT + o] = are[r] + vbr;
        out[(size_t)BB*NN*AOUT + (size_t)bn*AOUT + o] = aim[r] + vbi;
    }
}

// ---------------------------------------------------------------------------
// FUSED cooperative kernel: 2048 blocks x 128 threads, 2 grid syncs.
// ---------------------------------------------------------------------------
__global__ __launch_bounds__(128, 4) void fused_kernel(
    const float* __restrict__ Xr, const float* __restrict__ Xi,
    const float* __restrict__ Lr, const float* __restrict__ Li,
    const float* __restrict__ Wr, const float* __restrict__ Wi,
    const float* __restrict__ AWr, const float* __restrict__ AWi,
    const float* __restrict__ abr, const float* __restrict__ abi,
    const float* __restrict__ par, const float* __restrict__ pai,
    const float* __restrict__ bsr, const float* __restrict__ bsi,
    float* __restrict__ ws, char* __restrict__ wsB, float* __restrict__ out)
{
    cg::grid_group grid = cg::this_grid();
    __shared__ MainLds S;
    const int bid = blockIdx.x;
    const int t = threadIdx.x;

    // ---- Phase A: prep (blocks 0..191; others pass through) ----
    if (bid < 64) {
        prep_sisj(bid*32 + (t >> 2), t & 3, Xr, Xi, AWr, AWi, ws);
    } else if (bid < 128) {
        prep_packxt((bid - 64)*2 + (t >> 6), t & 63, Xr, Xi, wsB);
    } else if (bid < 192) {
        prep_packw((bid - 128)*128 + t, Wr, Wi, wsB);
    }
    __threadfence();
    grid.sync();

    // ---- Phase B: main, one block per (b,n) ----
    main_body(bid, t, S, Lr, Li, abr, abi, par, pai, ws, wsB);
    __threadfence();
    grid.sync();

    // ---- Phase C: out GEMM, 2048 wave-tasks on blocks 0..1023 ----
    if (bid < 1024) {
        out_body(bid*2 + (t >> 6), t & 63, wsB, bsr, bsi, out);
    }
}

// ---------------------------------------------------------------------------
// Fallback kernels (3-launch path, the round-5 31.9 µs configuration)
// ---------------------------------------------------------------------------
__global__ __launch_bounds__(256) void prep_kernel(
    const float* __restrict__ Xr, const float* __restrict__ Xi,
    const float* __restrict__ AWr, const float* __restrict__ AWi,
    const float* __restrict__ Wr, const float* __restrict__ Wi,
    float* __restrict__ ws, char* __restrict__ wsB)
{
    const int blk = blockIdx.x;
    const int t = threadIdx.x;
    if (blk < 32)       prep_sisj(blk*64 + (t >> 2), t & 3, Xr, Xi, AWr, AWi, ws);
    else if (blk < 64)  prep_packxt((blk - 32)*4 + (t >> 6), t & 63, Xr, Xi, wsB);
    else                prep_packw((blk - 64)*256 + t, Wr, Wi, wsB);
}

__global__ __launch_bounds__(128) void cheb_main_kernel(
    const float* __restrict__ Lr_g, const float* __restrict__ Li_g,
    const float* __restrict__ abr, const float* __restrict__ abi,
    const float* __restrict__ par, const float* __restrict__ pai,
    const float* __restrict__ ws, char* __restrict__ wsB)
{
    __shared__ MainLds S;
    main_body(blockIdx.x, threadIdx.x, S, Lr_g, Li_g, abr, abi, par, pai, ws, wsB);
}

__global__ __launch_bounds__(256) void out_gemm_kernel(
    const char* __restrict__ wsB,
    const float* __restrict__ bsr, const float* __restrict__ bsi,
    float* __restrict__ out)
{
    const int task = (blockIdx.x >> 2)*16 + (blockIdx.x & 3)*4 + (threadIdx.x >> 6);
    out_body(task, threadIdx.x & 63, wsB, bsr, bsi, out);
}

// ---------------------------------------------------------------------------
extern "C" void kernel_launch(void* const* d_in, const int* in_sizes, int n_in,
                              void* d_out, int out_size, void* d_ws, size_t ws_size,
                              hipStream_t stream)
{
    const float* Xr  = (const float*)d_in[0];
    const float* Xi  = (const float*)d_in[1];
    const float* Lr  = (const float*)d_in[2];
    const float* Li  = (const float*)d_in[3];
    const float* Wr  = (const float*)d_in[4];
    const float* Wi  = (const float*)d_in[5];
    const float* AWr = (const float*)d_in[6];
    const float* AWi = (const float*)d_in[7];
    const float* abr = (const float*)d_in[8];
    const float* abi = (const float*)d_in[9];
    const float* par = (const float*)d_in[10];
    const float* pai = (const float*)d_in[11];
    const float* bsr = (const float*)d_in[12];
    const float* bsi = (const float*)d_in[13];
    float* ws  = (float*)d_ws;
    char*  wsB = (char*)d_ws;
    float* out = (float*)d_out;

    void* args[] = { (void*)&Xr, (void*)&Xi, (void*)&Lr, (void*)&Li,
                     (void*)&Wr, (void*)&Wi, (void*)&AWr, (void*)&AWi,
                     (void*)&abr, (void*)&abi, (void*)&par, (void*)&pai,
                     (void*)&bsr, (void*)&bsi, (void*)&ws, (void*)&wsB, (void*)&out };
    hipError_t err = hipLaunchCooperativeKernel((void*)fused_kernel,
                                                dim3(BB*NN), dim3(128),
                                                args, 0, stream);
    if (err != hipSuccess) {
        // fallback: 3-kernel path (round-5 configuration)
        hipLaunchKernelGGL(prep_kernel, dim3(96), dim3(256), 0, stream,
                           Xr, Xi, AWr, AWi, Wr, Wi, ws, wsB);
        hipLaunchKernelGGL(cheb_main_kernel, dim3(BB*NN), dim3(128), 0, stream,
                           Lr, Li, abr, abi, par, pai, ws, wsB);
        hipLaunchKernelGGL(out_gemm_kernel, dim3(512), dim3(256), 0, stream,
                           wsB, bsr, bsi, out);
    }
}

// Round 11
// 38.315 us; speedup vs baseline: 17.0236x; 17.0236x over previous
//
#include <hip/hip_runtime.h>
#include <hip/hip_bf16.h>

#define BB 4
#define NN 512
#define CC 32
#define KK 4      // K+1
#define HH 4
#define AOUT 256

// ws float-index offsets (si/sj)
#define WS_SI_F   0
#define WS_SII_F  (BB*NN*HH)
#define WS_SJR_F  (2*BB*NN*HH)
#define WS_SJI_F  (3*BB*NN*HH)
// ws byte offsets
#define XT_BASE   131072                     // bf16 X tiles [part][b][jb16] x 2048 B
#define LX_BASE   393216                     // bf16 LX halves [bn][w] x 2048 B (8 MB)
#define BRE_BASE  (393216 + 2048*4096)       // bf16 B_re fragments, 128 KB
#define BIM_BASE  (BRE_BASE + 131072)        // bf16 B_im fragments, 128 KB

typedef __attribute__((ext_vector_type(8))) short bf16x8;
typedef __attribute__((ext_vector_type(4))) float f32x4;

__device__ __forceinline__ ushort f2bfu(float f){
    union { __hip_bfloat16 h; ushort u; } cv;
    cv.h = __float2bfloat16(f);
    return cv.u;
}
__device__ __forceinline__ short f2bfs(float f){ return (short)f2bfu(f); }
__device__ __forceinline__ float bfu2f(unsigned int u){ return __uint_as_float(u << 16); }

// ---------------------------------------------------------------------------
// Fused prep kernel: grid 96 x 256  (identical to round 5 except W base moved)
// ---------------------------------------------------------------------------
__global__ __launch_bounds__(256) void prep_kernel(
    const float* __restrict__ Xr, const float* __restrict__ Xi,
    const float* __restrict__ AWr, const float* __restrict__ AWi,
    const float* __restrict__ Wr, const float* __restrict__ Wi,
    float* __restrict__ ws, char* __restrict__ wsB)
{
    const int blk = blockIdx.x;
    const int t = threadIdx.x;

    if (blk < 32) {
        const int row = blk*64 + (t >> 2);
        const int q = t & 3;
        const float* xr = Xr + (size_t)row*CC + q*8;
        const float* xi = Xi + (size_t)row*CC + q*8;
        float4 xr4[2], xi4[2];
        xr4[0] = *(const float4*)xr;  xr4[1] = *(const float4*)(xr + 4);
        xi4[0] = *(const float4*)xi;  xi4[1] = *(const float4*)(xi + 4);

        float sir[HH] = {0,0,0,0}, sii[HH] = {0,0,0,0};
        float sjr[HH] = {0,0,0,0}, sji[HH] = {0,0,0,0};
        #pragma unroll
        for (int e = 0; e < 8; ++e) {
            float xrc = ((const float*)&xr4[e>>2])[e & 3];
            float xic = ((const float*)&xi4[e>>2])[e & 3];
            int c = q*8 + e;
            float4 w1r = *(const float4*)(AWr + c*HH);
            float4 w1i = *(const float4*)(AWi + c*HH);
            float4 w2r = *(const float4*)(AWr + (CC + c)*HH);
            float4 w2i = *(const float4*)(AWi + (CC + c)*HH);
            #pragma unroll
            for (int h = 0; h < HH; ++h) {
                float r1 = ((const float*)&w1r)[h], i1 = ((const float*)&w1i)[h];
                float r2 = ((const float*)&w2r)[h], i2 = ((const float*)&w2i)[h];
                sir[h] = fmaf(xrc, r1, fmaf(-xic, i1, sir[h]));
                sii[h] = fmaf(xrc, i1, fmaf( xic, r1, sii[h]));
                sjr[h] = fmaf(xrc, r2, fmaf(-xic, i2, sjr[h]));
                sji[h] = fmaf(xrc, i2, fmaf( xic, r2, sji[h]));
            }
        }
        float A[HH], Bv[HH];
        #pragma unroll
        for (int h = 0; h < HH; ++h) {
            float sendA = (q & 1) ? sir[h] : sii[h];
            float keepA = (q & 1) ? sii[h] : sir[h];
            A[h] = keepA + __shfl_xor(sendA, 1);
            float sendB = (q & 1) ? sjr[h] : sji[h];
            float keepB = (q & 1) ? sji[h] : sjr[h];
            Bv[h] = keepB + __shfl_xor(sendB, 1);
        }
        float tot[HH];
        #pragma unroll
        for (int h = 0; h < HH; ++h) {
            float send = (q & 2) ? A[h] : Bv[h];
            float keep = (q & 2) ? Bv[h] : A[h];
            tot[h] = keep + __shfl_xor(send, 2);
        }
        float4 v = make_float4(tot[0], tot[1], tot[2], tot[3]);
        *(float4*)(ws + (size_t)q*(BB*NN*HH) + (size_t)row*HH) = v;
    } else if (blk < 64) {
        int bid = (blk - 32)*4 + (t >> 6);   // 0..127: part*64 + b*16 + jb
        int part = bid >> 6, b = (bid >> 4) & 3, jb = bid & 15;
        const float* X = part ? Xi : Xr;
        int lane = t & 63;
        int c = lane & 31, jh = lane >> 5;

        unsigned int w[8];
        #pragma unroll
        for (int qq = 0; qq < 8; ++qq) {
            int ji = jh*16 + qq*2;
            float f0 = X[((size_t)b*NN + jb*32 + ji  )*CC + c];
            float f1 = X[((size_t)b*NN + jb*32 + ji+1)*CC + c];
            w[qq] = (unsigned int)f2bfu(f0) | ((unsigned int)f2bfu(f1) << 16);
        }
        char* tile = wsB + XT_BASE + (((size_t)(part*4 + b)*16 + jb) * 2048);
        uint4* dst = (uint4*)(tile + c*64 + jh*32);
        dst[0] = make_uint4(w[0], w[1], w[2], w[3]);
        dst[1] = make_uint4(w[4], w[5], w[6], w[7]);
    } else {
        // W fragment pack: idx over [h][Nt][s][lane]
        int idx = (blk - 64)*256 + t;        // 0..8191
        int l  = idx & 63;
        int s  = (idx >> 6) & 7;
        int Nt = (idx >> 9) & 3;
        int h  = idx >> 11;
        int p = Nt*16 + (l & 15), o = p*4 + h;
        int e8 = (l >> 4) * 8;
        unsigned int re_w[4], im_w[4];
        #pragma unroll
        for (int qq = 0; qq < 4; ++qq) {
            unsigned int rw = 0, iw = 0;
            #pragma unroll
            for (int half = 0; half < 2; ++half) {
                int kpos = s*32 + e8 + qq*2 + half;
                int ri = kpos >> 7, kk = (kpos >> 5) & 3, c = kpos & 31;
                float wr = Wr[(size_t)(kk*CC + c)*AOUT + o];
                float wi = Wi[(size_t)(kk*CC + c)*AOUT + o];
                unsigned int vre = f2bfu(ri ? -wi : wr);
                unsigned int vim = f2bfu(ri ?  wr : wi);
                rw |= vre << (16*half);
                iw |= vim << (16*half);
            }
            re_w[qq] = rw; im_w[qq] = iw;
        }
        size_t fo = ((size_t)((h*4 + Nt)*8 + s))*1024 + (size_t)l*16;
        *(uint4*)(wsB + BRE_BASE + fo) = make_uint4(re_w[0], re_w[1], re_w[2], re_w[3]);
        *(uint4*)(wsB + BIM_BASE + fo) = make_uint4(im_w[0], im_w[1], im_w[2], im_w[3]);
    }
}

// ---------------------------------------------------------------------------
// Main kernel: one block per (b,n), 128 threads (2 waves). LDS ~17 KB.
// Round-5 body; epilogue is BARRIER-FREE: each wave writes its own
// normalized half-partial LX to ws (out_gemm sums the halves).
// Barriers: 2 (S1, S2 only).
// ---------------------------------------------------------------------------
__global__ __launch_bounds__(128) void cheb_main_kernel(
    const float* __restrict__ Lr_g, const float* __restrict__ Li_g,
    const float* __restrict__ abr, const float* __restrict__ abi,
    const float* __restrict__ par, const float* __restrict__ pai,
    const float* __restrict__ ws, char* __restrict__ wsB)
{
    __shared__ ushort Lf[8][528];      // bf16 bits; 8448 B (rows: part*4+k)
    __shared__ float awf[HH][520];     // 8320 B
    __shared__ float wredm[2][HH];
    __shared__ float wreds[2][HH];

    const int bn = blockIdx.x;
    const int b = bn >> 9;
    const int n = bn & (NN - 1);
    const int t = threadIdx.x;
    const int l = t & 63;
    const int w = t >> 6;
    const int jw = 4*t;                // this thread's j-window (P1/P2)

    // ---- hoisted L2 loads: si, sj for j-window ----
    const float4 si_r4 = *(const float4*)(ws + WS_SI_F  + bn*HH);
    const float4 si_i4 = *(const float4*)(ws + WS_SII_F + bn*HH);
    float4 sjr[4], sji[4];
    #pragma unroll
    for (int e = 0; e < 4; ++e) {
        sjr[e] = *(const float4*)(ws + WS_SJR_F + ((size_t)b*NN + jw + e)*HH);
        sji[e] = *(const float4*)(ws + WS_SJI_F + ((size_t)b*NN + jw + e)*HH);
    }
    const float a_r = par[0], a_i = pai[0];

    // ---- P1: stage L as bf16; accumulate fp32 mask from Lr rows ----
    float am4[4] = {0.f,0.f,0.f,0.f};
    #pragma unroll
    for (int it = 0; it < 8; ++it) {
        const float* src = (it & 4) ? Li_g : Lr_g;
        size_t goff = (((size_t)b*KK + (it & 3))*NN + n)*NN + jw;
        float4 v = *(const float4*)(src + goff);
        if (it < 4) {
            am4[0] += fabsf(v.x); am4[1] += fabsf(v.y);
            am4[2] += fabsf(v.z); am4[3] += fabsf(v.w);
        }
        ushort4 u;
        u.x = f2bfu(v.x); u.y = f2bfu(v.y); u.z = f2bfu(v.z); u.w = f2bfu(v.w);
        *(ushort4*)&Lf[it][jw] = u;
    }

    // ---- P2a: scores in registers ----
    float sir[HH], sii[HH];
    #pragma unroll
    for (int h = 0; h < HH; ++h) {
        sir[h] = ((const float*)&si_r4)[h] + abr[h];
        sii[h] = ((const float*)&si_i4)[h] + abi[h];
    }
    float v[4][HH];
    float pmax[HH] = {-INFINITY, -INFINITY, -INFINITY, -INFINITY};
    #pragma unroll
    for (int e = 0; e < 4; ++e) {
        bool msk = am4[e] > 1e-9f;
        const float* sjrp = (const float*)&sjr[e];
        const float* sjip = (const float*)&sji[e];
        #pragma unroll
        for (int h = 0; h < HH; ++h) {
            float sr = sir[h] + sjrp[h];
            sr = sr >= 0.f ? sr : a_r * sr;
            float sv = sii[h] + sjip[h];
            sv = sv >= 0.f ? sv : a_i * sv;
            float val;
            if (msk) val = sr*sr + sv*sv;
            else { const float NEG = -1e9f; val = NEG*NEG + NEG*NEG; }
            v[e][h] = val;
            pmax[h] = fmaxf(pmax[h], val);
        }
    }
    #pragma unroll
    for (int h = 0; h < HH; ++h) {
        #pragma unroll
        for (int off = 32; off > 0; off >>= 1)
            pmax[h] = fmaxf(pmax[h], __shfl_xor(pmax[h], off));
    }
    if (l == 0) { wredm[w][0]=pmax[0]; wredm[w][1]=pmax[1]; wredm[w][2]=pmax[2]; wredm[w][3]=pmax[3]; }
    __syncthreads();                   // S1: Lf + wredm visible

    float hm[HH];
    #pragma unroll
    for (int h = 0; h < HH; ++h) hm[h] = fmaxf(wredm[0][h], wredm[1][h]);

    // ---- P2b: exp from registers, float4 awf writes ----
    float psum[HH];
    #pragma unroll
    for (int h = 0; h < HH; ++h) {
        float4 ev;
        ev.x = __expf(v[0][h] - hm[h]);
        ev.y = __expf(v[1][h] - hm[h]);
        ev.z = __expf(v[2][h] - hm[h]);
        ev.w = __expf(v[3][h] - hm[h]);
        *(float4*)&awf[h][jw] = ev;
        psum[h] = (ev.x + ev.y) + (ev.z + ev.w);
    }
    #pragma unroll
    for (int h = 0; h < HH; ++h) {
        #pragma unroll
        for (int off = 32; off > 0; off >>= 1)
            psum[h] += __shfl_xor(psum[h], off);
    }
    if (l == 0) { wreds[w][0]=psum[0]; wreds[w][1]=psum[1]; wreds[w][2]=psum[2]; wreds[w][3]=psum[3]; }
    __syncthreads();                   // S2: awf + wreds visible

    float inv[HH];
    #pragma unroll
    for (int h = 0; h < HH; ++h) inv[h] = 1.0f / (wreds[0][h] + wreds[1][h]);

    // ---- P3: MFMA, wave w owns j in [w*256, w*256+256), 8 steps, 2-deep pipe ----
    const int r_a = l & 15;            // A row = k*4+h
    const int jg  = l >> 4;
    const int k_a = r_a >> 2, h_a = r_a & 3;

    f32x4 acc[8];                      // RR0 RR1 II0 II1 RI0 RI1 IR0 IR1
    #pragma unroll
    for (int a = 0; a < 8; ++a) acc[a] = (f32x4){0.f,0.f,0.f,0.f};

    const char* xtR = wsB + XT_BASE + ((size_t)(0*4 + b)*16 + w*8)*2048;
    const char* xtI = wsB + XT_BASE + ((size_t)(4   + b)*16 + w*8)*2048;
    const int bofs = (l & 15)*64 + jg*16;

#define LOAD_STEP(s, BR0,BR1,BI0,BI1, LR8,LI8, AW0,AW1) do {                  \
        const int j0_ = w*256 + (s)*32 + jg*8;                                \
        BR0 = *(const bf16x8*)(xtR + (s)*2048 +        bofs);                 \
        BR1 = *(const bf16x8*)(xtR + (s)*2048 + 1024 + bofs);                 \
        BI0 = *(const bf16x8*)(xtI + (s)*2048 +        bofs);                 \
        BI1 = *(const bf16x8*)(xtI + (s)*2048 + 1024 + bofs);                 \
        LR8 = *(const bf16x8*)&Lf[k_a][j0_];                                  \
        LI8 = *(const bf16x8*)&Lf[4 + k_a][j0_];                              \
        AW0 = *(const float4*)&awf[h_a][j0_];                                 \
        AW1 = *(const float4*)&awf[h_a][j0_ + 4];                             \
    } while (0)

#define COMP_STEP(BR0,BR1,BI0,BI1, LR8,LI8, AW0,AW1) do {                     \
        float aww_[8];                                                        \
        *(float4*)&aww_[0] = AW0; *(float4*)&aww_[4] = AW1;                   \
        bf16x8 Ar_, Ai_;                                                      \
        _Pragma("unroll")                                                     \
        for (int e_ = 0; e_ < 8; ++e_) {                                      \
            Ar_[e_] = f2bfs(bfu2f((ushort)LR8[e_]) * aww_[e_]);               \
            Ai_[e_] = f2bfs(bfu2f((ushort)LI8[e_]) * aww_[e_]);               \
        }                                                                     \
        acc[0] = __builtin_amdgcn_mfma_f32_16x16x32_bf16(Ar_, BR0, acc[0],0,0,0); \
        acc[1] = __builtin_amdgcn_mfma_f32_16x16x32_bf16(Ar_, BR1, acc[1],0,0,0); \
        acc[2] = __builtin_amdgcn_mfma_f32_16x16x32_bf16(Ai_, BI0, acc[2],0,0,0); \
        acc[3] = __builtin_amdgcn_mfma_f32_16x16x32_bf16(Ai_, BI1, acc[3],0,0,0); \
        acc[4] = __builtin_amdgcn_mfma_f32_16x16x32_bf16(Ar_, BI0, acc[4],0,0,0); \
        acc[5] = __builtin_amdgcn_mfma_f32_16x16x32_bf16(Ar_, BI1, acc[5],0,0,0); \
        acc[6] = __builtin_amdgcn_mfma_f32_16x16x32_bf16(Ai_, BR0, acc[6],0,0,0); \
        acc[7] = __builtin_amdgcn_mfma_f32_16x16x32_bf16(Ai_, BR1, acc[7],0,0,0); \
    } while (0)

    {
        bf16x8 pBr0,pBr1,pBi0,pBi1,pLr,pLi; float4 pA0,pA1;
        bf16x8 qBr0,qBr1,qBi0,qBi1,qLr,qLi; float4 qA0,qA1;
        LOAD_STEP(0, pBr0,pBr1,pBi0,pBi1, pLr,pLi, pA0,pA1);
        LOAD_STEP(1, qBr0,qBr1,qBi0,qBi1, qLr,qLi, qA0,qA1);
        COMP_STEP(pBr0,pBr1,pBi0,pBi1, pLr,pLi, pA0,pA1);
        LOAD_STEP(2, pBr0,pBr1,pBi0,pBi1, pLr,pLi, pA0,pA1);
        COMP_STEP(qBr0,qBr1,qBi0,qBi1, qLr,qLi, qA0,qA1);
        LOAD_STEP(3, qBr0,qBr1,qBi0,qBi1, qLr,qLi, qA0,qA1);
        COMP_STEP(pBr0,pBr1,pBi0,pBi1, pLr,pLi, pA0,pA1);
        LOAD_STEP(4, pBr0,pBr1,pBi0,pBi1, pLr,pLi, pA0,pA1);
        COMP_STEP(qBr0,qBr1,qBi0,qBi1, qLr,qLi, qA0,qA1);
        LOAD_STEP(5, qBr0,qBr1,qBi0,qBi1, qLr,qLi, qA0,qA1);
        COMP_STEP(pBr0,pBr1,pBi0,pBi1, pLr,pLi, pA0,pA1);
        LOAD_STEP(6, pBr0,pBr1,pBi0,pBi1, pLr,pLi, pA0,pA1);
        COMP_STEP(qBr0,qBr1,qBi0,qBi1, qLr,qLi, qA0,qA1);
        LOAD_STEP(7, qBr0,qBr1,qBi0,qBi1, qLr,qLi, qA0,qA1);
        COMP_STEP(pBr0,pBr1,pBi0,pBi1, pLr,pLi, pA0,pA1);
        COMP_STEP(qBr0,qBr1,qBi0,qBi1, qLr,qLi, qA0,qA1);
    }
#undef LOAD_STEP
#undef COMP_STEP

    // ---- epilogue: BARRIER-FREE. Each wave writes its normalized half. ----
    // LX_half[bn][w]: layout within 2048B identical to before: [h(r)][ri][k][c]
    const int kk = l >> 4, lc = l & 15;
    char* lxp = wsB + LX_BASE + (size_t)bn*4096 + (size_t)w*2048;
    #pragma unroll
    for (int ct = 0; ct < 2; ++ct) {
        const int c = ct*16 + lc;
        #pragma unroll
        for (int r = 0; r < 4; ++r) {   // r == h
            float iv = inv[r];
            float vr = (acc[0+ct][r] - acc[2+ct][r]) * iv;
            float vi = (acc[4+ct][r] + acc[6+ct][r]) * iv;
            *(ushort*)(lxp + r*512 +       kk*64 + c*2) = f2bfu(vr);
            *(ushort*)(lxp + r*512 + 256 + kk*64 + c*2) = f2bfu(vi);
        }
    }
}

// ---------------------------------------------------------------------------
// Out GEMM: Y[bn,o] = (LX0+LX1) @ Bre/Bim (K=256 per half), + bias.
// grid 512 blocks (Mtile*4 + Nt) x 256 thr; wave = h.
// B fragments loaded once per s; both halves accumulate into same acc.
// ---------------------------------------------------------------------------
__global__ __launch_bounds__(256) void out_gemm_kernel(
    const char* __restrict__ wsB,
    const float* __restrict__ bsr, const float* __restrict__ bsi,
    float* __restrict__ out)
{
    const int Mtile = blockIdx.x >> 2;
    const int Nt    = blockIdx.x & 3;
    const int t = threadIdx.x, l = t & 63, h = t >> 6;

    const char* abase0 = wsB + LX_BASE + ((size_t)(Mtile*16 + (l & 15)))*4096
                         + h*512 + (l >> 4)*16;
    const char* abase1 = abase0 + 2048;
    f32x4 are = (f32x4){0.f,0.f,0.f,0.f};
    f32x4 aim = (f32x4){0.f,0.f,0.f,0.f};
    const size_t fbase = ((size_t)((h*4 + Nt)*8))*1024 + (size_t)l*16;
    const char* bre = wsB + BRE_BASE + fbase;
    const char* bim = wsB + BIM_BASE + fbase;
    #pragma unroll
    for (int s = 0; s < 8; ++s) {
        bf16x8 Af0 = *(const bf16x8*)(abase0 + s*64);
        bf16x8 Af1 = *(const bf16x8*)(abase1 + s*64);
        bf16x8 Br  = *(const bf16x8*)(bre + s*1024);
        bf16x8 Bi  = *(const bf16x8*)(bim + s*1024);
        are = __builtin_amdgcn_mfma_f32_16x16x32_bf16(Af0, Br, are, 0, 0, 0);
        are = __builtin_amdgcn_mfma_f32_16x16x32_bf16(Af1, Br, are, 0, 0, 0);
        aim = __builtin_amdgcn_mfma_f32_16x16x32_bf16(Af0, Bi, aim, 0, 0, 0);
        aim = __builtin_amdgcn_mfma_f32_16x16x32_bf16(Af1, Bi, aim, 0, 0, 0);
    }
    const int p = Nt*16 + (l & 15), o = p*4 + h;
    const float vbr = bsr[o], vbi = bsi[o];
    #pragma unroll
    for (int r = 0; r < 4; ++r) {
        int bn = Mtile*16 + (l >> 4)*4 + r;
        out[(size_t)bn*AOUT + o] = are[r] + vbr;
        out[(size_t)BB*NN*AOUT + (size_t)bn*AOUT + o] = aim[r] + vbi;
    }
}

// ---------------------------------------------------------------------------
extern "C" void kernel_launch(void* const* d_in, const int* in_sizes, int n_in,
                              void* d_out, int out_size, void* d_ws, size_t ws_size,
                              hipStream_t stream)
{
    const float* Xr  = (const float*)d_in[0];
    const float* Xi  = (const float*)d_in[1];
    const float* Lr  = (const float*)d_in[2];
    const float* Li  = (const float*)d_in[3];
    const float* Wr  = (const float*)d_in[4];
    const float* Wi  = (const float*)d_in[5];
    const float* AWr = (const float*)d_in[6];
    const float* AWi = (const float*)d_in[7];
    const float* abr = (const float*)d_in[8];
    const float* abi = (const float*)d_in[9];
    const float* par = (const float*)d_in[10];
    const float* pai = (const float*)d_in[11];
    const float* bsr = (const float*)d_in[12];
    const float* bsi = (const float*)d_in[13];
    float* ws  = (float*)d_ws;
    char*  wsB = (char*)d_ws;
    float* out = (float*)d_out;

    hipLaunchKernelGGL(prep_kernel, dim3(96), dim3(256), 0, stream,
                       Xr, Xi, AWr, AWi, Wr, Wi, ws, wsB);
    hipLaunchKernelGGL(cheb_main_kernel, dim3(BB*NN), dim3(128), 0, stream,
                       Lr, Li, abr, abi, par, pai, ws, wsB);
    hipLaunchKernelGGL(out_gemm_kernel, dim3(512), dim3(256), 0, stream,
                       wsB, bsr, bsi, out);
}

// Round 12
// 34.080 us; speedup vs baseline: 19.1392x; 1.1243x over previous
//
#include <hip/hip_runtime.h>
#include <hip/hip_bf16.h>

#define BB 4
#define NN 512
#define CC 32
#define KK 4      // K+1
#define HH 4
#define AOUT 256

// ws float-index offsets (si/sj)
#define WS_SI_F   0
#define WS_SII_F  (BB*NN*HH)
#define WS_SJR_F  (2*BB*NN*HH)
#define WS_SJI_F  (3*BB*NN*HH)
// ws byte offsets
#define XT_BASE   131072         // bf16 X tiles [part][b][jb16] x 2048 B
#define LX_BASE   393216         // bf16 LX [bn] x 2048 B   (4 MB)
#define BRE_BASE  4587520        // bf16 B_re fragments, 128 KB
#define BIM_BASE  4718592        // bf16 B_im fragments, 128 KB

typedef __attribute__((ext_vector_type(8))) short bf16x8;
typedef __attribute__((ext_vector_type(4))) float f32x4;

__device__ __forceinline__ ushort f2bfu(float f){
    union { __hip_bfloat16 h; ushort u; } cv;
    cv.h = __float2bfloat16(f);
    return cv.u;
}
__device__ __forceinline__ short f2bfs(float f){ return (short)f2bfu(f); }
__device__ __forceinline__ float bfu2f(unsigned int u){ return __uint_as_float(u << 16); }

// ---------------------------------------------------------------------------
// Fused prep kernel: grid 96 x 256   (identical to round 5)
// ---------------------------------------------------------------------------
__global__ __launch_bounds__(256) void prep_kernel(
    const float* __restrict__ Xr, const float* __restrict__ Xi,
    const float* __restrict__ AWr, const float* __restrict__ AWi,
    const float* __restrict__ Wr, const float* __restrict__ Wi,
    float* __restrict__ ws, char* __restrict__ wsB)
{
    const int blk = blockIdx.x;
    const int t = threadIdx.x;

    if (blk < 32) {
        const int row = blk*64 + (t >> 2);
        const int q = t & 3;
        const float* xr = Xr + (size_t)row*CC + q*8;
        const float* xi = Xi + (size_t)row*CC + q*8;
        float4 xr4[2], xi4[2];
        xr4[0] = *(const float4*)xr;  xr4[1] = *(const float4*)(xr + 4);
        xi4[0] = *(const float4*)xi;  xi4[1] = *(const float4*)(xi + 4);

        float sir[HH] = {0,0,0,0}, sii[HH] = {0,0,0,0};
        float sjr[HH] = {0,0,0,0}, sji[HH] = {0,0,0,0};
        #pragma unroll
        for (int e = 0; e < 8; ++e) {
            float xrc = ((const float*)&xr4[e>>2])[e & 3];
            float xic = ((const float*)&xi4[e>>2])[e & 3];
            int c = q*8 + e;
            float4 w1r = *(const float4*)(AWr + c*HH);
            float4 w1i = *(const float4*)(AWi + c*HH);
            float4 w2r = *(const float4*)(AWr + (CC + c)*HH);
            float4 w2i = *(const float4*)(AWi + (CC + c)*HH);
            #pragma unroll
            for (int h = 0; h < HH; ++h) {
                float r1 = ((const float*)&w1r)[h], i1 = ((const float*)&w1i)[h];
                float r2 = ((const float*)&w2r)[h], i2 = ((const float*)&w2i)[h];
                sir[h] = fmaf(xrc, r1, fmaf(-xic, i1, sir[h]));
                sii[h] = fmaf(xrc, i1, fmaf( xic, r1, sii[h]));
                sjr[h] = fmaf(xrc, r2, fmaf(-xic, i2, sjr[h]));
                sji[h] = fmaf(xrc, i2, fmaf( xic, r2, sji[h]));
            }
        }
        float A[HH], Bv[HH];
        #pragma unroll
        for (int h = 0; h < HH; ++h) {
            float sendA = (q & 1) ? sir[h] : sii[h];
            float keepA = (q & 1) ? sii[h] : sir[h];
            A[h] = keepA + __shfl_xor(sendA, 1);
            float sendB = (q & 1) ? sjr[h] : sji[h];
            float keepB = (q & 1) ? sji[h] : sjr[h];
            Bv[h] = keepB + __shfl_xor(sendB, 1);
        }
        float tot[HH];
        #pragma unroll
        for (int h = 0; h < HH; ++h) {
            float send = (q & 2) ? A[h] : Bv[h];
            float keep = (q & 2) ? Bv[h] : A[h];
            tot[h] = keep + __shfl_xor(send, 2);
        }
        float4 v = make_float4(tot[0], tot[1], tot[2], tot[3]);
        *(float4*)(ws + (size_t)q*(BB*NN*HH) + (size_t)row*HH) = v;
    } else if (blk < 64) {
        int bid = (blk - 32)*4 + (t >> 6);   // 0..127: part*64 + b*16 + jb
        int part = bid >> 6, b = (bid >> 4) & 3, jb = bid & 15;
        const float* X = part ? Xi : Xr;
        int lane = t & 63;
        int c = lane & 31, jh = lane >> 5;

        unsigned int w[8];
        #pragma unroll
        for (int qq = 0; qq < 8; ++qq) {
            int ji = jh*16 + qq*2;
            float f0 = X[((size_t)b*NN + jb*32 + ji  )*CC + c];
            float f1 = X[((size_t)b*NN + jb*32 + ji+1)*CC + c];
            w[qq] = (unsigned int)f2bfu(f0) | ((unsigned int)f2bfu(f1) << 16);
        }
        char* tile = wsB + XT_BASE + (((size_t)(part*4 + b)*16 + jb) * 2048);
        uint4* dst = (uint4*)(tile + c*64 + jh*32);
        dst[0] = make_uint4(w[0], w[1], w[2], w[3]);
        dst[1] = make_uint4(w[4], w[5], w[6], w[7]);
    } else {
        // W fragment pack: idx over [h][Nt][s][lane]
        int idx = (blk - 64)*256 + t;        // 0..8191
        int l  = idx & 63;
        int s  = (idx >> 6) & 7;
        int Nt = (idx >> 9) & 3;
        int h  = idx >> 11;
        int p = Nt*16 + (l & 15), o = p*4 + h;
        int e8 = (l >> 4) * 8;
        unsigned int re_w[4], im_w[4];
        #pragma unroll
        for (int qq = 0; qq < 4; ++qq) {
            unsigned int rw = 0, iw = 0;
            #pragma unroll
            for (int half = 0; half < 2; ++half) {
                int kpos = s*32 + e8 + qq*2 + half;
                int ri = kpos >> 7, kk = (kpos >> 5) & 3, c = kpos & 31;
                float wr = Wr[(size_t)(kk*CC + c)*AOUT + o];
                float wi = Wi[(size_t)(kk*CC + c)*AOUT + o];
                unsigned int vre = f2bfu(ri ? -wi : wr);
                unsigned int vim = f2bfu(ri ?  wr : wi);
                rw |= vre << (16*half);
                iw |= vim << (16*half);
            }
            re_w[qq] = rw; im_w[qq] = iw;
        }
        size_t fo = ((size_t)((h*4 + Nt)*8 + s))*1024 + (size_t)l*16;
        *(uint4*)(wsB + BRE_BASE + fo) = make_uint4(re_w[0], re_w[1], re_w[2], re_w[3]);
        *(uint4*)(wsB + BIM_BASE + fo) = make_uint4(im_w[0], im_w[1], im_w[2], im_w[3]);
    }
}

// ---------------------------------------------------------------------------
// Main kernel: one block per (b,n), 128 threads (2 waves). LDS ~17 KB.
// Round-5 body verbatim + T5 s_setprio around each MFMA cluster.
// ---------------------------------------------------------------------------
__global__ __launch_bounds__(128) void cheb_main_kernel(
    const float* __restrict__ Lr_g, const float* __restrict__ Li_g,
    const float* __restrict__ abr, const float* __restrict__ abi,
    const float* __restrict__ par, const float* __restrict__ pai,
    const float* __restrict__ ws, char* __restrict__ wsB)
{
    __shared__ ushort Lf[8][528];      // bf16 bits; 8448 B (rows: part*4+k)
    __shared__ float awf[HH][520];     // 8320 B; reused as pbuf (2048 floats)
    __shared__ float wredm[2][HH];
    __shared__ float wreds[2][HH];

    const int bn = blockIdx.x;
    const int b = bn >> 9;
    const int n = bn & (NN - 1);
    const int t = threadIdx.x;
    const int l = t & 63;
    const int w = t >> 6;
    const int jw = 4*t;                // this thread's j-window (P1/P2)

    // ---- hoisted L2 loads: si, sj for j-window ----
    const float4 si_r4 = *(const float4*)(ws + WS_SI_F  + bn*HH);
    const float4 si_i4 = *(const float4*)(ws + WS_SII_F + bn*HH);
    float4 sjr[4], sji[4];
    #pragma unroll
    for (int e = 0; e < 4; ++e) {
        sjr[e] = *(const float4*)(ws + WS_SJR_F + ((size_t)b*NN + jw + e)*HH);
        sji[e] = *(const float4*)(ws + WS_SJI_F + ((size_t)b*NN + jw + e)*HH);
    }
    const float a_r = par[0], a_i = pai[0];

    // ---- P1: stage L as bf16; accumulate fp32 mask from Lr rows ----
    float am4[4] = {0.f,0.f,0.f,0.f};
    #pragma unroll
    for (int it = 0; it < 8; ++it) {
        const float* src = (it & 4) ? Li_g : Lr_g;
        size_t goff = (((size_t)b*KK + (it & 3))*NN + n)*NN + jw;
        float4 v = *(const float4*)(src + goff);
        if (it < 4) {
            am4[0] += fabsf(v.x); am4[1] += fabsf(v.y);
            am4[2] += fabsf(v.z); am4[3] += fabsf(v.w);
        }
        ushort4 u;
        u.x = f2bfu(v.x); u.y = f2bfu(v.y); u.z = f2bfu(v.z); u.w = f2bfu(v.w);
        *(ushort4*)&Lf[it][jw] = u;
    }

    // ---- P2a: scores in registers ----
    float sir[HH], sii[HH];
    #pragma unroll
    for (int h = 0; h < HH; ++h) {
        sir[h] = ((const float*)&si_r4)[h] + abr[h];
        sii[h] = ((const float*)&si_i4)[h] + abi[h];
    }
    float v[4][HH];
    float pmax[HH] = {-INFINITY, -INFINITY, -INFINITY, -INFINITY};
    #pragma unroll
    for (int e = 0; e < 4; ++e) {
        bool msk = am4[e] > 1e-9f;
        const float* sjrp = (const float*)&sjr[e];
        const float* sjip = (const float*)&sji[e];
        #pragma unroll
        for (int h = 0; h < HH; ++h) {
            float sr = sir[h] + sjrp[h];
            sr = sr >= 0.f ? sr : a_r * sr;
            float sv = sii[h] + sjip[h];
            sv = sv >= 0.f ? sv : a_i * sv;
            float val;
            if (msk) val = sr*sr + sv*sv;
            else { const float NEG = -1e9f; val = NEG*NEG + NEG*NEG; }
            v[e][h] = val;
            pmax[h] = fmaxf(pmax[h], val);
        }
    }
    #pragma unroll
    for (int h = 0; h < HH; ++h) {
        #pragma unroll
        for (int off = 32; off > 0; off >>= 1)
            pmax[h] = fmaxf(pmax[h], __shfl_xor(pmax[h], off));
    }
    if (l == 0) { wredm[w][0]=pmax[0]; wredm[w][1]=pmax[1]; wredm[w][2]=pmax[2]; wredm[w][3]=pmax[3]; }
    __syncthreads();                   // S1: Lf + wredm visible

    float hm[HH];
    #pragma unroll
    for (int h = 0; h < HH; ++h) hm[h] = fmaxf(wredm[0][h], wredm[1][h]);

    // ---- P2b: exp from registers, float4 awf writes ----
    float psum[HH];
    #pragma unroll
    for (int h = 0; h < HH; ++h) {
        float4 ev;
        ev.x = __expf(v[0][h] - hm[h]);
        ev.y = __expf(v[1][h] - hm[h]);
        ev.z = __expf(v[2][h] - hm[h]);
        ev.w = __expf(v[3][h] - hm[h]);
        *(float4*)&awf[h][jw] = ev;
        psum[h] = (ev.x + ev.y) + (ev.z + ev.w);
    }
    #pragma unroll
    for (int h = 0; h < HH; ++h) {
        #pragma unroll
        for (int off = 32; off > 0; off >>= 1)
            psum[h] += __shfl_xor(psum[h], off);
    }
    if (l == 0) { wreds[w][0]=psum[0]; wreds[w][1]=psum[1]; wreds[w][2]=psum[2]; wreds[w][3]=psum[3]; }
    __syncthreads();                   // S2: awf + wreds visible

    float inv[HH];
    #pragma unroll
    for (int h = 0; h < HH; ++h) inv[h] = 1.0f / (wreds[0][h] + wreds[1][h]);

    // ---- P3: MFMA, wave w owns j in [w*256, w*256+256), 8 steps, 2-deep pipe ----
    const int r_a = l & 15;            // A row = k*4+h
    const int jg  = l >> 4;
    const int k_a = r_a >> 2, h_a = r_a & 3;

    f32x4 acc[8];                      // RR0 RR1 II0 II1 RI0 RI1 IR0 IR1
    #pragma unroll
    for (int a = 0; a < 8; ++a) acc[a] = (f32x4){0.f,0.f,0.f,0.f};

    const char* xtR = wsB + XT_BASE + ((size_t)(0*4 + b)*16 + w*8)*2048;
    const char* xtI = wsB + XT_BASE + ((size_t)(4   + b)*16 + w*8)*2048;
    const int bofs = (l & 15)*64 + jg*16;

#define LOAD_STEP(s, BR0,BR1,BI0,BI1, LR8,LI8, AW0,AW1) do {                  \
        const int j0_ = w*256 + (s)*32 + jg*8;                                \
        BR0 = *(const bf16x8*)(xtR + (s)*2048 +        bofs);                 \
        BR1 = *(const bf16x8*)(xtR + (s)*2048 + 1024 + bofs);                 \
        BI0 = *(const bf16x8*)(xtI + (s)*2048 +        bofs);                 \
        BI1 = *(const bf16x8*)(xtI + (s)*2048 + 1024 + bofs);                 \
        LR8 = *(const bf16x8*)&Lf[k_a][j0_];                                  \
        LI8 = *(const bf16x8*)&Lf[4 + k_a][j0_];                              \
        AW0 = *(const float4*)&awf[h_a][j0_];                                 \
        AW1 = *(const float4*)&awf[h_a][j0_ + 4];                             \
    } while (0)

#define COMP_STEP(BR0,BR1,BI0,BI1, LR8,LI8, AW0,AW1) do {                     \
        float aww_[8];                                                        \
        *(float4*)&aww_[0] = AW0; *(float4*)&aww_[4] = AW1;                   \
        bf16x8 Ar_, Ai_;                                                      \
        _Pragma("unroll")                                                     \
        for (int e_ = 0; e_ < 8; ++e_) {                                      \
            Ar_[e_] = f2bfs(bfu2f((ushort)LR8[e_]) * aww_[e_]);               \
            Ai_[e_] = f2bfs(bfu2f((ushort)LI8[e_]) * aww_[e_]);               \
        }                                                                     \
        __builtin_amdgcn_s_setprio(1);                                        \
        acc[0] = __builtin_amdgcn_mfma_f32_16x16x32_bf16(Ar_, BR0, acc[0],0,0,0); \
        acc[1] = __builtin_amdgcn_mfma_f32_16x16x32_bf16(Ar_, BR1, acc[1],0,0,0); \
        acc[2] = __builtin_amdgcn_mfma_f32_16x16x32_bf16(Ai_, BI0, acc[2],0,0,0); \
        acc[3] = __builtin_amdgcn_mfma_f32_16x16x32_bf16(Ai_, BI1, acc[3],0,0,0); \
        acc[4] = __builtin_amdgcn_mfma_f32_16x16x32_bf16(Ar_, BI0, acc[4],0,0,0); \
        acc[5] = __builtin_amdgcn_mfma_f32_16x16x32_bf16(Ar_, BI1, acc[5],0,0,0); \
        acc[6] = __builtin_amdgcn_mfma_f32_16x16x32_bf16(Ai_, BR0, acc[6],0,0,0); \
        acc[7] = __builtin_amdgcn_mfma_f32_16x16x32_bf16(Ai_, BR1, acc[7],0,0,0); \
        __builtin_amdgcn_s_setprio(0);                                        \
    } while (0)

    {
        bf16x8 pBr0,pBr1,pBi0,pBi1,pLr,pLi; float4 pA0,pA1;
        bf16x8 qBr0,qBr1,qBi0,qBi1,qLr,qLi; float4 qA0,qA1;
        LOAD_STEP(0, pBr0,pBr1,pBi0,pBi1, pLr,pLi, pA0,pA1);
        LOAD_STEP(1, qBr0,qBr1,qBi0,qBi1, qLr,qLi, qA0,qA1);
        COMP_STEP(pBr0,pBr1,pBi0,pBi1, pLr,pLi, pA0,pA1);
        LOAD_STEP(2, pBr0,pBr1,pBi0,pBi1, pLr,pLi, pA0,pA1);
        COMP_STEP(qBr0,qBr1,qBi0,qBi1, qLr,qLi, qA0,qA1);
        LOAD_STEP(3, qBr0,qBr1,qBi0,qBi1, qLr,qLi, qA0,qA1);
        COMP_STEP(pBr0,pBr1,pBi0,pBi1, pLr,pLi, pA0,pA1);
        LOAD_STEP(4, pBr0,pBr1,pBi0,pBi1, pLr,pLi, pA0,pA1);
        COMP_STEP(qBr0,qBr1,qBi0,qBi1, qLr,qLi, qA0,qA1);
        LOAD_STEP(5, qBr0,qBr1,qBi0,qBi1, qLr,qLi, qA0,qA1);
        COMP_STEP(pBr0,pBr1,pBi0,pBi1, pLr,pLi, pA0,pA1);
        LOAD_STEP(6, pBr0,pBr1,pBi0,pBi1, pLr,pLi, pA0,pA1);
        COMP_STEP(qBr0,qBr1,qBi0,qBi1, qLr,qLi, qA0,qA1);
        LOAD_STEP(7, qBr0,qBr1,qBi0,qBi1, qLr,qLi, qA0,qA1);
        COMP_STEP(pBr0,pBr1,pBi0,pBi1, pLr,pLi, pA0,pA1);
        COMP_STEP(qBr0,qBr1,qBi0,qBi1, qLr,qLi, qA0,qA1);
    }
#undef LOAD_STEP
#undef COMP_STEP

    __syncthreads();                   // S3: all awf/Lf reads done

    float* pbuf = &awf[0][0];
    if (w == 1) {
        #pragma unroll
        for (int a = 0; a < 8; ++a)
            #pragma unroll
            for (int r = 0; r < 4; ++r)
                pbuf[(a*4 + r)*64 + l] = acc[a][r];
    }
    __syncthreads();                   // S4
    if (w == 0) {
        const int kk = l >> 4, lc = l & 15;
        #pragma unroll
        for (int a = 0; a < 8; ++a)
            #pragma unroll
            for (int r = 0; r < 4; ++r)
                acc[a][r] += pbuf[(a*4 + r)*64 + l];
        // LX bf16: [bn](2048B) layout [h(r)][ri][k][c]
        char* lxp = wsB + LX_BASE + (size_t)bn*2048;
        #pragma unroll
        for (int ct = 0; ct < 2; ++ct) {
            const int c = ct*16 + lc;
            #pragma unroll
            for (int r = 0; r < 4; ++r) {   // r == h
                float iv = inv[r];
                float vr = (acc[0+ct][r] - acc[2+ct][r]) * iv;
                float vi = (acc[4+ct][r] + acc[6+ct][r]) * iv;
                *(ushort*)(lxp + r*512 +       kk*64 + c*2) = f2bfu(vr);
                *(ushort*)(lxp + r*512 + 256 + kk*64 + c*2) = f2bfu(vi);
            }
        }
    }
}

// ---------------------------------------------------------------------------
// Out GEMM: Y[bn,o] = [LXr|LXi] @ Bre/Bim (K=256), + bias.
// grid 512 blocks (Mtile*4 + Nt) x 256 thr; wave = h.   (round-5 verbatim)
// ---------------------------------------------------------------------------
__global__ __launch_bounds__(256) void out_gemm_kernel(
    const char* __restrict__ wsB,
    const float* __restrict__ bsr, const float* __restrict__ bsi,
    float* __restrict__ out)
{
    const int Mtile = blockIdx.x >> 2;
    const int Nt    = blockIdx.x & 3;
    const int t = threadIdx.x, l = t & 63, h = t >> 6;

    const char* abase = wsB + LX_BASE + ((size_t)(Mtile*16 + (l & 15)))*2048
                        + h*512 + (l >> 4)*16;
    f32x4 are = (f32x4){0.f,0.f,0.f,0.f};
    f32x4 aim = (f32x4){0.f,0.f,0.f,0.f};
    const size_t fbase = ((size_t)((h*4 + Nt)*8))*1024 + (size_t)l*16;
    const char* bre = wsB + BRE_BASE + fbase;
    const char* bim = wsB + BIM_BASE + fbase;
    #pragma unroll
    for (int s = 0; s < 8; ++s) {
        bf16x8 Af = *(const bf16x8*)(abase + s*64);
        bf16x8 Br = *(const bf16x8*)(bre + s*1024);
        bf16x8 Bi = *(const bf16x8*)(bim + s*1024);
        are = __builtin_amdgcn_mfma_f32_16x16x32_bf16(Af, Br, are, 0, 0, 0);
        aim = __builtin_amdgcn_mfma_f32_16x16x32_bf16(Af, Bi, aim, 0, 0, 0);
    }
    const int p = Nt*16 + (l & 15), o = p*4 + h;
    const float vbr = bsr[o], vbi = bsi[o];
    #pragma unroll
    for (int r = 0; r < 4; ++r) {
        int bn = Mtile*16 + (l >> 4)*4 + r;
        out[(size_t)bn*AOUT + o] = are[r] + vbr;
        out[(size_t)BB*NN*AOUT + (size_t)bn*AOUT + o] = aim[r] + vbi;
    }
}

// ---------------------------------------------------------------------------
extern "C" void kernel_launch(void* const* d_in, const int* in_sizes, int n_in,
                              void* d_out, int out_size, void* d_ws, size_t ws_size,
                              hipStream_t stream)
{
    const float* Xr  = (const float*)d_in[0];
    const float* Xi  = (const float*)d_in[1];
    const float* Lr  = (const float*)d_in[2];
    const float* Li  = (const float*)d_in[3];
    const float* Wr  = (const float*)d_in[4];
    const float* Wi  = (const float*)d_in[5];
    const float* AWr = (const float*)d_in[6];
    const float* AWi = (const float*)d_in[7];
    const float* abr = (const float*)d_in[8];
    const float* abi = (const float*)d_in[9];
    const float* par = (const float*)d_in[10];
    const float* pai = (const float*)d_in[11];
    const float* bsr = (const float*)d_in[12];
    const float* bsi = (const float*)d_in[13];
    float* ws  = (float*)d_ws;
    char*  wsB = (char*)d_ws;
    float* out = (float*)d_out;

    hipLaunchKernelGGL(prep_kernel, dim3(96), dim3(256), 0, stream,
                       Xr, Xi, AWr, AWi, Wr, Wi, ws, wsB);
    hipLaunchKernelGGL(cheb_main_kernel, dim3(BB*NN), dim3(128), 0, stream,
                       Lr, Li, abr, abi, par, pai, ws, wsB);
    hipLaunchKernelGGL(out_gemm_kernel, dim3(512), dim3(256), 0, stream,
                       wsB, bsr, bsi, out);
}

// Round 13
// 32.215 us; speedup vs baseline: 20.2476x; 1.0579x over previous
//
#include <hip/hip_runtime.h>
#include <hip/hip_bf16.h>

#define BB 4
#define NN 512
#define CC 32
#define KK 4      // K+1
#define HH 4
#define AOUT 256

// ws float-index offsets (si/sj)
#define WS_SI_F   0
#define WS_SII_F  (BB*NN*HH)
#define WS_SJR_F  (2*BB*NN*HH)
#define WS_SJI_F  (3*BB*NN*HH)
// ws byte offsets
#define XT_BASE   131072         // bf16 X tiles [part][b][jb16] x 2048 B
#define LX_BASE   393216         // bf16 LX [bn] x 2048 B   (4 MB)
#define BRE_BASE  4587520        // bf16 B_re fragments, 128 KB
#define BIM_BASE  4718592        // bf16 B_im fragments, 128 KB

typedef __attribute__((ext_vector_type(8))) short bf16x8;
typedef __attribute__((ext_vector_type(4))) float f32x4;

__device__ __forceinline__ ushort f2bfu(float f){
    union { __hip_bfloat16 h; ushort u; } cv;
    cv.h = __float2bfloat16(f);
    return cv.u;
}
__device__ __forceinline__ short f2bfs(float f){ return (short)f2bfu(f); }
__device__ __forceinline__ float bfu2f(unsigned int u){ return __uint_as_float(u << 16); }

// ---------------------------------------------------------------------------
// Fused prep kernel: grid 72 x 256
//  blk 0..7   : si/sj attention projections
//  blk 8..39  : pack X -> bf16 tiles (tile 32j x 32c = 2 KB; byte = c*64+(j&31)*2)
//  blk 40..71 : pack W -> B-fragment layout for out GEMM
// ---------------------------------------------------------------------------
__global__ __launch_bounds__(256) void prep_kernel(
    const float* __restrict__ Xr, const float* __restrict__ Xi,
    const float* __restrict__ AWr, const float* __restrict__ AWi,
    const float* __restrict__ Wr, const float* __restrict__ Wi,
    float* __restrict__ ws, char* __restrict__ wsB)
{
    const int blk = blockIdx.x;
    const int t = threadIdx.x;

    if (blk < 8) {
        int idx = blk*256 + t;
        const float* xr = Xr + (size_t)idx * CC;
        const float* xi = Xi + (size_t)idx * CC;
        float sir[HH] = {0,0,0,0}, sii[HH] = {0,0,0,0};
        float sjr[HH] = {0,0,0,0}, sji[HH] = {0,0,0,0};
        for (int c = 0; c < CC; ++c) {
            float xrc = xr[c], xic = xi[c];
            const float* w1r = AWr + c*HH;
            const float* w1i = AWi + c*HH;
            const float* w2r = AWr + (CC + c)*HH;
            const float* w2i = AWi + (CC + c)*HH;
            #pragma unroll
            for (int h = 0; h < HH; ++h) {
                sir[h] = fmaf(xrc, w1r[h], fmaf(-xic, w1i[h], sir[h]));
                sii[h] = fmaf(xrc, w1i[h], fmaf( xic, w1r[h], sii[h]));
                sjr[h] = fmaf(xrc, w2r[h], fmaf(-xic, w2i[h], sjr[h]));
                sji[h] = fmaf(xrc, w2i[h], fmaf( xic, w2r[h], sji[h]));
            }
        }
        #pragma unroll
        for (int h = 0; h < HH; ++h) {
            ws[WS_SI_F  + idx*HH + h] = sir[h];
            ws[WS_SII_F + idx*HH + h] = sii[h];
            ws[WS_SJR_F + idx*HH + h] = sjr[h];
            ws[WS_SJI_F + idx*HH + h] = sji[h];
        }
    } else if (blk < 40) {
        int bid = (blk - 8)*4 + (t >> 6);    // 0..127: part*64 + b*16 + jb
        int part = bid >> 6, b = (bid >> 4) & 3, jb = bid & 15;
        const float* X = part ? Xi : Xr;
        int lane = t & 63;
        int c = lane & 31, jh = lane >> 5;

        unsigned int w[8];
        #pragma unroll
        for (int q = 0; q < 8; ++q) {
            int ji = jh*16 + q*2;
            float f0 = X[((size_t)b*NN + jb*32 + ji  )*CC + c];
            float f1 = X[((size_t)b*NN + jb*32 + ji+1)*CC + c];
            w[q] = (unsigned int)f2bfu(f0) | ((unsigned int)f2bfu(f1) << 16);
        }
        char* tile = wsB + XT_BASE + (((size_t)(part*4 + b)*16 + jb) * 2048);
        uint4* dst = (uint4*)(tile + c*64 + jh*32);
        dst[0] = make_uint4(w[0], w[1], w[2], w[3]);
        dst[1] = make_uint4(w[4], w[5], w[6], w[7]);
    } else {
        // W fragment pack: idx over [h][Nt][s][lane]
        int idx = (blk - 40)*256 + t;        // 0..8191
        int l  = idx & 63;
        int s  = (idx >> 6) & 7;
        int Nt = (idx >> 9) & 3;
        int h  = idx >> 11;
        int p = Nt*16 + (l & 15), o = p*4 + h;
        int e8 = (l >> 4) * 8;
        unsigned int re_w[4], im_w[4];
        #pragma unroll
        for (int q = 0; q < 4; ++q) {
            unsigned int rw = 0, iw = 0;
            #pragma unroll
            for (int half = 0; half < 2; ++half) {
                int kpos = s*32 + e8 + q*2 + half;
                int ri = kpos >> 7, kk = (kpos >> 5) & 3, c = kpos & 31;
                float wr = Wr[(size_t)(kk*CC + c)*AOUT + o];
                float wi = Wi[(size_t)(kk*CC + c)*AOUT + o];
                unsigned int vre = f2bfu(ri ? -wi : wr);
                unsigned int vim = f2bfu(ri ?  wr : wi);
                rw |= vre << (16*half);
                iw |= vim << (16*half);
            }
            re_w[q] = rw; im_w[q] = iw;
        }
        size_t fo = ((size_t)((h*4 + Nt)*8 + s))*1024 + (size_t)l*16;
        *(uint4*)(wsB + BRE_BASE + fo) = make_uint4(re_w[0], re_w[1], re_w[2], re_w[3]);
        *(uint4*)(wsB + BIM_BASE + fo) = make_uint4(im_w[0], im_w[1], im_w[2], im_w[3]);
    }
}

// ---------------------------------------------------------------------------
// Main kernel: one block per (b,n), 128 threads (2 waves). LDS ~17 KB.
//  P1: L fp32 -> bf16 LDS; thread t sees ALL 8 rows at j=4t..4t+3 -> reg mask
//  P2: scores in registers (si/sj hoisted); exp from regs; float4 awf writes
//  P3: MFMA, 2-deep software-pipelined B-fragment loads, fully unrolled
//  reduce: single pbuf round; w0 writes normalized LX bf16
// ---------------------------------------------------------------------------
__global__ __launch_bounds__(128) void cheb_main_kernel(
    const float* __restrict__ Lr_g, const float* __restrict__ Li_g,
    const float* __restrict__ abr, const float* __restrict__ abi,
    const float* __restrict__ par, const float* __restrict__ pai,
    const float* __restrict__ ws, char* __restrict__ wsB)
{
    __shared__ ushort Lf[8][528];      // bf16 bits; 8448 B (rows: part*4+k)
    __shared__ float awf[HH][520];     // 8320 B; reused as pbuf (2048 floats)
    __shared__ float wredm[2][HH];
    __shared__ float wreds[2][HH];

    const int bn = blockIdx.x;
    const int b = bn >> 9;
    const int n = bn & (NN - 1);
    const int t = threadIdx.x;
    const int l = t & 63;
    const int w = t >> 6;
    const int jw = 4*t;                // this thread's j-window (P1/P2)

    // ---- hoisted L2 loads: si, sj for j-window ----
    const float4 si_r4 = *(const float4*)(ws + WS_SI_F  + bn*HH);
    const float4 si_i4 = *(const float4*)(ws + WS_SII_F + bn*HH);
    float4 sjr[4], sji[4];
    #pragma unroll
    for (int e = 0; e < 4; ++e) {
        sjr[e] = *(const float4*)(ws + WS_SJR_F + ((size_t)b*NN + jw + e)*HH);
        sji[e] = *(const float4*)(ws + WS_SJI_F + ((size_t)b*NN + jw + e)*HH);
    }
    const float a_r = par[0], a_i = pai[0];

    // ---- P1: stage L as bf16; accumulate fp32 mask from Lr rows ----
    float am4[4] = {0.f,0.f,0.f,0.f};
    #pragma unroll
    for (int it = 0; it < 8; ++it) {
        const float* src = (it & 4) ? Li_g : Lr_g;
        size_t goff = (((size_t)b*KK + (it & 3))*NN + n)*NN + jw;
        float4 v = *(const float4*)(src + goff);
        if (it < 4) {
            am4[0] += fabsf(v.x); am4[1] += fabsf(v.y);
            am4[2] += fabsf(v.z); am4[3] += fabsf(v.w);
        }
        ushort4 u;
        u.x = f2bfu(v.x); u.y = f2bfu(v.y); u.z = f2bfu(v.z); u.w = f2bfu(v.w);
        *(ushort4*)&Lf[it][jw] = u;
    }

    // ---- P2a: scores in registers ----
    float sir[HH], sii[HH];
    #pragma unroll
    for (int h = 0; h < HH; ++h) {
        sir[h] = ((const float*)&si_r4)[h] + abr[h];
        sii[h] = ((const float*)&si_i4)[h] + abi[h];
    }
    float v[4][HH];
    float pmax[HH] = {-INFINITY, -INFINITY, -INFINITY, -INFINITY};
    #pragma unroll
    for (int e = 0; e < 4; ++e) {
        bool msk = am4[e] > 1e-9f;
        const float* sjrp = (const float*)&sjr[e];
        const float* sjip = (const float*)&sji[e];
        #pragma unroll
        for (int h = 0; h < HH; ++h) {
            float sr = sir[h] + sjrp[h];
            sr = sr >= 0.f ? sr : a_r * sr;
            float sv = sii[h] + sjip[h];
            sv = sv >= 0.f ? sv : a_i * sv;
            float val;
            if (msk) val = sr*sr + sv*sv;
            else { const float NEG = -1e9f; val = NEG*NEG + NEG*NEG; }
            v[e][h] = val;
            pmax[h] = fmaxf(pmax[h], val);
        }
    }
    #pragma unroll
    for (int h = 0; h < HH; ++h) {
        #pragma unroll
        for (int off = 32; off > 0; off >>= 1)
            pmax[h] = fmaxf(pmax[h], __shfl_xor(pmax[h], off));
    }
    if (l == 0) { wredm[w][0]=pmax[0]; wredm[w][1]=pmax[1]; wredm[w][2]=pmax[2]; wredm[w][3]=pmax[3]; }
    __syncthreads();                   // S1: Lf + wredm visible

    float hm[HH];
    #pragma unroll
    for (int h = 0; h < HH; ++h) hm[h] = fmaxf(wredm[0][h], wredm[1][h]);

    // ---- P2b: exp from registers, float4 awf writes ----
    float psum[HH];
    #pragma unroll
    for (int h = 0; h < HH; ++h) {
        float4 ev;
        ev.x = __expf(v[0][h] - hm[h]);
        ev.y = __expf(v[1][h] - hm[h]);
        ev.z = __expf(v[2][h] - hm[h]);
        ev.w = __expf(v[3][h] - hm[h]);
        *(float4*)&awf[h][jw] = ev;
        psum[h] = (ev.x + ev.y) + (ev.z + ev.w);
    }
    #pragma unroll
    for (int h = 0; h < HH; ++h) {
        #pragma unroll
        for (int off = 32; off > 0; off >>= 1)
            psum[h] += __shfl_xor(psum[h], off);
    }
    if (l == 0) { wreds[w][0]=psum[0]; wreds[w][1]=psum[1]; wreds[w][2]=psum[2]; wreds[w][3]=psum[3]; }
    __syncthreads();                   // S2: awf + wreds visible

    float inv[HH];
    #pragma unroll
    for (int h = 0; h < HH; ++h) inv[h] = 1.0f / (wreds[0][h] + wreds[1][h]);

    // ---- P3: MFMA, wave w owns j in [w*256, w*256+256), 8 steps, 2-deep pipe ----
    const int r_a = l & 15;            // A row = k*4+h
    const int jg  = l >> 4;
    const int k_a = r_a >> 2, h_a = r_a & 3;

    f32x4 acc[8];                      // RR0 RR1 II0 II1 RI0 RI1 IR0 IR1
    #pragma unroll
    for (int a = 0; a < 8; ++a) acc[a] = (f32x4){0.f,0.f,0.f,0.f};

    const char* xtR = wsB + XT_BASE + ((size_t)(0*4 + b)*16 + w*8)*2048;
    const char* xtI = wsB + XT_BASE + ((size_t)(4   + b)*16 + w*8)*2048;
    const int bofs = (l & 15)*64 + jg*16;

#define LOAD_STEP(s, BR0,BR1,BI0,BI1, LR8,LI8, AW0,AW1) do {                  \
        const int j0_ = w*256 + (s)*32 + jg*8;                                \
        BR0 = *(const bf16x8*)(xtR + (s)*2048 +        bofs);                 \
        BR1 = *(const bf16x8*)(xtR + (s)*2048 + 1024 + bofs);                 \
        BI0 = *(const bf16x8*)(xtI + (s)*2048 +        bofs);                 \
        BI1 = *(const bf16x8*)(xtI + (s)*2048 + 1024 + bofs);                 \
        LR8 = *(const bf16x8*)&Lf[k_a][j0_];                                  \
        LI8 = *(const bf16x8*)&Lf[4 + k_a][j0_];                              \
        AW0 = *(const float4*)&awf[h_a][j0_];                                 \
        AW1 = *(const float4*)&awf[h_a][j0_ + 4];                             \
    } while (0)

#define COMP_STEP(BR0,BR1,BI0,BI1, LR8,LI8, AW0,AW1) do {                     \
        float aww_[8];                                                        \
        *(float4*)&aww_[0] = AW0; *(float4*)&aww_[4] = AW1;                   \
        bf16x8 Ar_, Ai_;                                                      \
        _Pragma("unroll")                                                     \
        for (int e_ = 0; e_ < 8; ++e_) {                                      \
            Ar_[e_] = f2bfs(bfu2f((ushort)LR8[e_]) * aww_[e_]);               \
            Ai_[e_] = f2bfs(bfu2f((ushort)LI8[e_]) * aww_[e_]);               \
        }                                                                     \
        acc[0] = __builtin_amdgcn_mfma_f32_16x16x32_bf16(Ar_, BR0, acc[0],0,0,0); \
        acc[1] = __builtin_amdgcn_mfma_f32_16x16x32_bf16(Ar_, BR1, acc[1],0,0,0); \
        acc[2] = __builtin_amdgcn_mfma_f32_16x16x32_bf16(Ai_, BI0, acc[2],0,0,0); \
        acc[3] = __builtin_amdgcn_mfma_f32_16x16x32_bf16(Ai_, BI1, acc[3],0,0,0); \
        acc[4] = __builtin_amdgcn_mfma_f32_16x16x32_bf16(Ar_, BI0, acc[4],0,0,0); \
        acc[5] = __builtin_amdgcn_mfma_f32_16x16x32_bf16(Ar_, BI1, acc[5],0,0,0); \
        acc[6] = __builtin_amdgcn_mfma_f32_16x16x32_bf16(Ai_, BR0, acc[6],0,0,0); \
        acc[7] = __builtin_amdgcn_mfma_f32_16x16x32_bf16(Ai_, BR1, acc[7],0,0,0); \
    } while (0)

    {
        bf16x8 pBr0,pBr1,pBi0,pBi1,pLr,pLi; float4 pA0,pA1;
        bf16x8 qBr0,qBr1,qBi0,qBi1,qLr,qLi; float4 qA0,qA1;
        LOAD_STEP(0, pBr0,pBr1,pBi0,pBi1, pLr,pLi, pA0,pA1);
        LOAD_STEP(1, qBr0,qBr1,qBi0,qBi1, qLr,qLi, qA0,qA1);
        COMP_STEP(pBr0,pBr1,pBi0,pBi1, pLr,pLi, pA0,pA1);
        LOAD_STEP(2, pBr0,pBr1,pBi0,pBi1, pLr,pLi, pA0,pA1);
        COMP_STEP(qBr0,qBr1,qBi0,qBi1, qLr,qLi, qA0,qA1);
        LOAD_STEP(3, qBr0,qBr1,qBi0,qBi1, qLr,qLi, qA0,qA1);
        COMP_STEP(pBr0,pBr1,pBi0,pBi1, pLr,pLi, pA0,pA1);
        LOAD_STEP(4, pBr0,pBr1,pBi0,pBi1, pLr,pLi, pA0,pA1);
        COMP_STEP(qBr0,qBr1,qBi0,qBi1, qLr,qLi, qA0,qA1);
        LOAD_STEP(5, qBr0,qBr1,qBi0,qBi1, qLr,qLi, qA0,qA1);
        COMP_STEP(pBr0,pBr1,pBi0,pBi1, pLr,pLi, pA0,pA1);
        LOAD_STEP(6, pBr0,pBr1,pBi0,pBi1, pLr,pLi, pA0,pA1);
        COMP_STEP(qBr0,qBr1,qBi0,qBi1, qLr,qLi, qA0,qA1);
        LOAD_STEP(7, qBr0,qBr1,qBi0,qBi1, qLr,qLi, qA0,qA1);
        COMP_STEP(pBr0,pBr1,pBi0,pBi1, pLr,pLi, pA0,pA1);
        COMP_STEP(qBr0,qBr1,qBi0,qBi1, qLr,qLi, qA0,qA1);
    }
#undef LOAD_STEP
#undef COMP_STEP

    __syncthreads();                   // S3: all awf/Lf reads done

    float* pbuf = &awf[0][0];
    if (w == 1) {
        #pragma unroll
        for (int a = 0; a < 8; ++a)
            #pragma unroll
            for (int r = 0; r < 4; ++r)
                pbuf[(a*4 + r)*64 + l] = acc[a][r];
    }
    __syncthreads();                   // S4
    if (w == 0) {
        const int kk = l >> 4, lc = l & 15;
        #pragma unroll
        for (int a = 0; a < 8; ++a)
            #pragma unroll
            for (int r = 0; r < 4; ++r)
                acc[a][r] += pbuf[(a*4 + r)*64 + l];
        // LX bf16: [bn](2048B) layout [h(r)][ri][k][c]
        char* lxp = wsB + LX_BASE + (size_t)bn*2048;
        #pragma unroll
        for (int ct = 0; ct < 2; ++ct) {
            const int c = ct*16 + lc;
            #pragma unroll
            for (int r = 0; r < 4; ++r) {   // r == h
                float iv = inv[r];
                float vr = (acc[0+ct][r] - acc[2+ct][r]) * iv;
                float vi = (acc[4+ct][r] + acc[6+ct][r]) * iv;
                *(ushort*)(lxp + r*512 +       kk*64 + c*2) = f2bfu(vr);
                *(ushort*)(lxp + r*512 + 256 + kk*64 + c*2) = f2bfu(vi);
            }
        }
    }
}

// ---------------------------------------------------------------------------
// Out GEMM: Y[bn,o] = [LXr|LXi] @ Bre/Bim (K=256), + bias.
// grid 512 blocks (Mtile*4 + Nt) x 256 thr; wave = h.
// ---------------------------------------------------------------------------
__global__ __launch_bounds__(256) void out_gemm_kernel(
    const char* __restrict__ wsB,
    const float* __restrict__ bsr, const float* __restrict__ bsi,
    float* __restrict__ out)
{
    const int Mtile = blockIdx.x >> 2;
    const int Nt    = blockIdx.x & 3;
    const int t = threadIdx.x, l = t & 63, h = t >> 6;

    const char* abase = wsB + LX_BASE + ((size_t)(Mtile*16 + (l & 15)))*2048
                        + h*512 + (l >> 4)*16;
    f32x4 are = (f32x4){0.f,0.f,0.f,0.f};
    f32x4 aim = (f32x4){0.f,0.f,0.f,0.f};
    const size_t fbase = ((size_t)((h*4 + Nt)*8))*1024 + (size_t)l*16;
    const char* bre = wsB + BRE_BASE + fbase;
    const char* bim = wsB + BIM_BASE + fbase;
    #pragma unroll
    for (int s = 0; s < 8; ++s) {
        bf16x8 Af = *(const bf16x8*)(abase + s*64);
        bf16x8 Br = *(const bf16x8*)(bre + s*1024);
        bf16x8 Bi = *(const bf16x8*)(bim + s*1024);
        are = __builtin_amdgcn_mfma_f32_16x16x32_bf16(Af, Br, are, 0, 0, 0);
        aim = __builtin_amdgcn_mfma_f32_16x16x32_bf16(Af, Bi, aim, 0, 0, 0);
    }
    const int p = Nt*16 + (l & 15), o = p*4 + h;
    const float vbr = bsr[o], vbi = bsi[o];
    #pragma unroll
    for (int r = 0; r < 4; ++r) {
        int bn = Mtile*16 + (l >> 4)*4 + r;
        out[(size_t)bn*AOUT + o] = are[r] + vbr;
        out[(size_t)BB*NN*AOUT + (size_t)bn*AOUT + o] = aim[r] + vbi;
    }
}

// ---------------------------------------------------------------------------
extern "C" void kernel_launch(void* const* d_in, const int* in_sizes, int n_in,
                              void* d_out, int out_size, void* d_ws, size_t ws_size,
                              hipStream_t stream)
{
    const float* Xr  = (const float*)d_in[0];
    const float* Xi  = (const float*)d_in[1];
    const float* Lr  = (const float*)d_in[2];
    const float* Li  = (const float*)d_in[3];
    const float* Wr  = (const float*)d_in[4];
    const float* Wi  = (const float*)d_in[5];
    const float* AWr = (const float*)d_in[6];
    const float* AWi = (const float*)d_in[7];
    const float* abr = (const float*)d_in[8];
    const float* abi = (const float*)d_in[9];
    const float* par = (const float*)d_in[10];
    const float* pai = (const float*)d_in[11];
    const float* bsr = (const float*)d_in[12];
    const float* bsi = (const float*)d_in[13];
    float* ws  = (float*)d_ws;
    char*  wsB = (char*)d_ws;
    float* out = (float*)d_out;

    hipLaunchKernelGGL(prep_kernel, dim3(72), dim3(256), 0, stream,
                       Xr, Xi, AWr, AWi, Wr, Wi, ws, wsB);
    hipLaunchKernelGGL(cheb_main_kernel, dim3(BB*NN), dim3(128), 0, stream,
                       Lr, Li, abr, abi, par, pai, ws, wsB);
    hipLaunchKernelGGL(out_gemm_kernel, dim3(512), dim3(256), 0, stream,
                       wsB, bsr, bsi, out);
}